// Round 3
// baseline (453.439 us; speedup 1.0000x reference)
//
#include <hip/hip_runtime.h>
#include <hip/hip_bf16.h>
#include <math.h>

#define Hdim 1024
#define Vdim 50257
#define Bdim 64
#define Tdim 2048

#define TCH 64
#define NCHUNK (Tdim / TCH)  // 32
#define PSTRIDE (Hdim + 4)

typedef short bf16x8 __attribute__((ext_vector_type(8)));
typedef float f32x4 __attribute__((ext_vector_type(4)));

__device__ __forceinline__ unsigned short f2bf(float f) {
  unsigned int u = __float_as_uint(f);
  unsigned int r = u + 0x7FFFu + ((u >> 16) & 1u);  // RNE
  return (unsigned short)(r >> 16);
}

// ---------------- embed + concat ----------------
__global__ void k_embed_concat(const int* __restrict__ idx, const float* __restrict__ E,
                               const float* __restrict__ context,
                               float* __restrict__ x, float* __restrict__ emb) {
  int i = blockIdx.x * blockDim.x + threadIdx.x;
  if (i >= Bdim * Hdim) return;
  int b = i >> 10, h = i & 1023;
  float e = E[(long)idx[b] * Hdim + h];
  emb[i] = e;
  x[(long)b * 2 * Hdim + h] = e;
  x[(long)b * 2 * Hdim + Hdim + h] = context[i];
}

// ---------------- split-K fp32 GEMM, M=64 tile, N tile 64 ----------------
// Cpart[sk][64][ldc] partial = A[64, kBase:kBase+kLen] @ op(W)
template <bool TRANSW>
__global__ void k_gemm_sk(const float* __restrict__ A, int lda,
                          const float* __restrict__ W, int ldw,
                          float* __restrict__ Cpart, int ldc, int N, int kLen) {
  __shared__ float As[16][68];
  __shared__ float Ws[16][68];
  int tid = threadIdx.x;
  int tx = tid & 15, ty = tid >> 4;
  int n0 = blockIdx.x * 64;
  int kBase = blockIdx.y * kLen;
  float acc[4][4];
#pragma unroll
  for (int i = 0; i < 4; i++)
#pragma unroll
    for (int j = 0; j < 4; j++) acc[i][j] = 0.f;

  for (int k0 = kBase; k0 < kBase + kLen; k0 += 16) {
    {
      int m = tid >> 2;
      int kk = (tid & 3) << 2;
      float4 av = *(const float4*)(A + (long)m * lda + k0 + kk);
      As[kk + 0][m] = av.x; As[kk + 1][m] = av.y;
      As[kk + 2][m] = av.z; As[kk + 3][m] = av.w;
    }
    if (!TRANSW) {
      int n = tid >> 2;
      int kk = (tid & 3) << 2;
      long gn = n0 + n;
      float4 wv = make_float4(0.f, 0.f, 0.f, 0.f);
      if (gn < N) wv = *(const float4*)(W + gn * (long)ldw + k0 + kk);
      Ws[kk + 0][n] = wv.x; Ws[kk + 1][n] = wv.y;
      Ws[kk + 2][n] = wv.z; Ws[kk + 3][n] = wv.w;
    } else {
      int kk = tid >> 4;
      int n4 = (tid & 15) << 2;
      float4 wv = *(const float4*)(W + (long)(k0 + kk) * ldw + n0 + n4);
      *(float4*)&Ws[kk][n4] = wv;
    }
    __syncthreads();
#pragma unroll
    for (int k = 0; k < 16; ++k) {
      float4 a = *(const float4*)&As[k][ty << 2];
      float4 w = *(const float4*)&Ws[k][tx << 2];
      acc[0][0] += a.x * w.x; acc[0][1] += a.x * w.y; acc[0][2] += a.x * w.z; acc[0][3] += a.x * w.w;
      acc[1][0] += a.y * w.x; acc[1][1] += a.y * w.y; acc[1][2] += a.y * w.z; acc[1][3] += a.y * w.w;
      acc[2][0] += a.z * w.x; acc[2][1] += a.z * w.y; acc[2][2] += a.z * w.z; acc[2][3] += a.z * w.w;
      acc[3][0] += a.w * w.x; acc[3][1] += a.w * w.y; acc[3][2] += a.w * w.z; acc[3][3] += a.w * w.w;
    }
    __syncthreads();
  }
  float* C = Cpart + (long)blockIdx.y * 64 * ldc;
#pragma unroll
  for (int i = 0; i < 4; i++) {
    int m = (ty << 2) + i;
#pragma unroll
    for (int j = 0; j < 4; j++) {
      int n = n0 + (tx << 2) + j;
      if (n < N) C[(long)m * ldc + n] = acc[i][j];
    }
  }
}

// ---------------- GRU gate fusion + split-K combine ----------------
__global__ void k_gru_gate2(const float* __restrict__ gi_part, int ski,
                            const float* __restrict__ gh_part, int skh,
                            const float* __restrict__ b_ih, const float* __restrict__ b_hh,
                            const float* __restrict__ hprev, float* __restrict__ hout) {
  int i = blockIdx.x * blockDim.x + threadIdx.x;
  if (i >= Bdim * Hdim) return;
  int b = i >> 10, h = i & 1023;
  float ir = b_ih[h], iz = b_ih[Hdim + h], in = b_ih[2 * Hdim + h];
  float hr = b_hh[h], hz = b_hh[Hdim + h], hn = b_hh[2 * Hdim + h];
  for (int s = 0; s < ski; ++s) {
    const float* g = gi_part + ((long)s * 64 + b) * 3072;
    ir += g[h]; iz += g[Hdim + h]; in += g[2 * Hdim + h];
  }
  for (int s = 0; s < skh; ++s) {
    const float* g = gh_part + ((long)s * 64 + b) * 3072;
    hr += g[h]; hz += g[Hdim + h]; hn += g[2 * Hdim + h];
  }
  float r = 1.f / (1.f + __expf(-(ir + hr)));
  float z = 1.f / (1.f + __expf(-(iz + hz)));
  float n = tanhf(in + r * hn);
  hout[i] = (1.f - z) * n + z * hprev[i];
}

// ---------------- q = sum of split-K partials ----------------
__global__ void k_qcomb(const float* __restrict__ qp, float* __restrict__ q) {
  int i = blockIdx.x * 256 + threadIdx.x;  // 65536 total
  float s = 0.f;
#pragma unroll
  for (int k = 0; k < 8; ++k) s += qp[(long)k * 65536 + i];
  q[i] = s;
}

// ---------------- cb[b] = h1[b,:] . ba ----------------
__global__ void k_cb(const float* __restrict__ h1, const float* __restrict__ ba,
                     float* __restrict__ cb) {
  int b = blockIdx.x;
  int tid = threadIdx.x;  // 256
  float p = 0.f;
  for (int h = tid; h < Hdim; h += 256) p += h1[(long)b * Hdim + h] * ba[h];
#pragma unroll
  for (int off = 32; off > 0; off >>= 1) p += __shfl_down(p, off, 64);
  __shared__ float red[4];
  if ((tid & 63) == 0) red[tid >> 6] = p;
  __syncthreads();
  if (tid == 0) cb[b] = red[0] + red[1] + red[2] + red[3];
}

// ---------------- h1 -> catb (bf16) cols [0,H) ----------------
__global__ void k_h1_to_catb(const float* __restrict__ h1, unsigned short* __restrict__ catb) {
  int i = blockIdx.x * blockDim.x + threadIdx.x;  // 16384
  if (i >= Bdim * Hdim / 4) return;
  int b = i >> 8, p = i & 255;
  float4 v = ((const float4*)(h1 + (long)b * Hdim))[p];
  ushort4 o;
  o.x = f2bf(v.x); o.y = f2bf(v.y); o.z = f2bf(v.z); o.w = f2bf(v.w);
  *(ushort4*)(catb + (long)b * 2 * Hdim + p * 4) = o;
}

// ---------------- scores + online-softmax partial context (wave-per-row) ----
__global__ __launch_bounds__(256) void k_scores_ctx(
    const float* __restrict__ enc, const float* __restrict__ q,
    const float* __restrict__ cb, float* __restrict__ scores,
    float* __restrict__ part) {
  int b = blockIdx.y, ch = blockIdx.x;
  int tid = threadIdx.x, w = tid >> 6, lane = tid & 63;
  __shared__ float s_acc[4][Hdim];
  __shared__ float s_ml[4][2];
  const float4* q4 = (const float4*)(q + (long)b * Hdim);
  float4 q0 = q4[lane], q1 = q4[lane + 64], q2 = q4[lane + 128], q3 = q4[lane + 192];
  float cbb = cb[b];
  float m = -INFINITY, l = 0.f;
  float4 a0 = make_float4(0, 0, 0, 0), a1 = a0, a2 = a0, a3 = a0;
  int tbase = ch * TCH + w * 16;
  for (int i = 0; i < 16; ++i) {
    int t = tbase + i;
    const float4* e4 = (const float4*)(enc + ((long)t * Bdim + b) * Hdim);
    float4 e0 = e4[lane], e1 = e4[lane + 64], e2 = e4[lane + 128], e3 = e4[lane + 192];
    float p = q0.x * e0.x + q0.y * e0.y + q0.z * e0.z + q0.w * e0.w
            + q1.x * e1.x + q1.y * e1.y + q1.z * e1.z + q1.w * e1.w
            + q2.x * e2.x + q2.y * e2.y + q2.z * e2.z + q2.w * e2.w
            + q3.x * e3.x + q3.y * e3.y + q3.z * e3.z + q3.w * e3.w;
#pragma unroll
    for (int off = 1; off < 64; off <<= 1) p += __shfl_xor(p, off, 64);
    float s = p + cbb;
    if (lane == 0) scores[(long)b * Tdim + t] = s;
    float mn = fmaxf(m, s);
    float sc = __expf(m - mn);  // exp(-inf)=0 on first iter
    float wt = __expf(s - mn);
    l = l * sc + wt;
    a0.x = a0.x * sc + wt * e0.x; a0.y = a0.y * sc + wt * e0.y;
    a0.z = a0.z * sc + wt * e0.z; a0.w = a0.w * sc + wt * e0.w;
    a1.x = a1.x * sc + wt * e1.x; a1.y = a1.y * sc + wt * e1.y;
    a1.z = a1.z * sc + wt * e1.z; a1.w = a1.w * sc + wt * e1.w;
    a2.x = a2.x * sc + wt * e2.x; a2.y = a2.y * sc + wt * e2.y;
    a2.z = a2.z * sc + wt * e2.z; a2.w = a2.w * sc + wt * e2.w;
    a3.x = a3.x * sc + wt * e3.x; a3.y = a3.y * sc + wt * e3.y;
    a3.z = a3.z * sc + wt * e3.z; a3.w = a3.w * sc + wt * e3.w;
    m = mn;
  }
  float4* sa = (float4*)s_acc[w];
  sa[lane] = a0; sa[lane + 64] = a1; sa[lane + 128] = a2; sa[lane + 192] = a3;
  if (lane == 0) { s_ml[w][0] = m; s_ml[w][1] = l; }
  __syncthreads();
  float M = fmaxf(fmaxf(s_ml[0][0], s_ml[1][0]), fmaxf(s_ml[2][0], s_ml[3][0]));
  float L = 0.f;
  float4 o = make_float4(0, 0, 0, 0);
  for (int ww = 0; ww < 4; ++ww) {
    float wgt = __expf(s_ml[ww][0] - M);
    L += wgt * s_ml[ww][1];
    float4 v = ((const float4*)s_acc[ww])[tid];
    o.x += wgt * v.x; o.y += wgt * v.y; o.z += wgt * v.z; o.w += wgt * v.w;
  }
  float* pp = part + ((long)b * NCHUNK + ch) * PSTRIDE;
  ((float4*)pp)[tid] = o;
  if (tid == 0) { pp[Hdim] = M; pp[Hdim + 1] = L; }
}

// ---------------- combine partials -> context (fp32 out + bf16 into catb) ----
__global__ void k_ctx_combine(const float* __restrict__ part, float* __restrict__ ctx_out,
                              unsigned short* __restrict__ catb, float* __restrict__ ml) {
  int b = blockIdx.x, tid = threadIdx.x;  // 256
  __shared__ float ms[NCHUNK], ls[NCHUNK];
  if (tid < NCHUNK) {
    const float* pp = part + ((long)b * NCHUNK + tid) * PSTRIDE;
    ms[tid] = pp[Hdim];
    ls[tid] = pp[Hdim + 1];
  }
  __syncthreads();
  float m = -INFINITY;
  for (int c = 0; c < NCHUNK; ++c) m = fmaxf(m, ms[c]);
  float l = 0.f;
  for (int c = 0; c < NCHUNK; ++c) l += __expf(ms[c] - m) * ls[c];
  float4 a = make_float4(0, 0, 0, 0);
  for (int c = 0; c < NCHUNK; ++c) {
    float w = __expf(ms[c] - m);
    float4 v = ((const float4*)(part + ((long)b * NCHUNK + c) * PSTRIDE))[tid];
    a.x += w * v.x; a.y += w * v.y; a.z += w * v.z; a.w += w * v.w;
  }
  float inv = 1.f / l;
  a.x *= inv; a.y *= inv; a.z *= inv; a.w *= inv;
  ((float4*)(ctx_out + (long)b * Hdim))[tid] = a;
  ushort4 o;
  o.x = f2bf(a.x); o.y = f2bf(a.y); o.z = f2bf(a.z); o.w = f2bf(a.w);
  *(ushort4*)(catb + (long)b * 2 * Hdim + Hdim + tid * 4) = o;
  if (tid == 0) { ml[2 * b] = m; ml[2 * b + 1] = l; }
}

// ---------------- attn weights output ----------------
__global__ void k_attn(const float* __restrict__ scores, const float* __restrict__ ml,
                       float* __restrict__ attn) {
  int i = blockIdx.x * blockDim.x + threadIdx.x;
  if (i >= Bdim * Tdim) return;
  int b = i >> 11;
  attn[i] = __expf(scores[i] - ml[2 * b]) / ml[2 * b + 1];
}

// ---------------- new_hidden = stack(h0,h1) + emb ----------------
__global__ void k_hidden_out(const float* __restrict__ h0, const float* __restrict__ h1,
                             const float* __restrict__ emb, float* __restrict__ out) {
  int i = blockIdx.x * blockDim.x + threadIdx.x;
  if (i >= 2 * Bdim * Hdim) return;
  int r = i & (Bdim * Hdim - 1);
  float hv = (i < Bdim * Hdim) ? h0[r] : h1[r];
  out[i] = hv + emb[r];
}

// ---------------- Wo GEMM: bf16 MFMA, fp32 Wo converted in load path ----------
// out[64, V] = tanh(catb[64, 2H] @ Wo[V, 2H].T + bo)
__global__ __launch_bounds__(256) void k_wo_mfma(const unsigned short* __restrict__ catb,
                                                 const float* __restrict__ Wo,
                                                 const float* __restrict__ bo,
                                                 float* __restrict__ out) {
  int tid = threadIdx.x, w = tid >> 6, lane = tid & 63;
  int n = blockIdx.x * 64 + w * 16 + (lane & 15);
  bool valid = n < Vdim;
  const float* wrow = Wo + (long)(valid ? n : 0) * (2 * Hdim);
  int kb = (lane >> 4) * 8;
  int r16 = lane & 15;
  const unsigned short* ar0 = catb + (long)(r16) * 2048 + kb;
  const unsigned short* ar1 = catb + (long)(16 + r16) * 2048 + kb;
  const unsigned short* ar2 = catb + (long)(32 + r16) * 2048 + kb;
  const unsigned short* ar3 = catb + (long)(48 + r16) * 2048 + kb;
  f32x4 acc0 = {0.f, 0.f, 0.f, 0.f}, acc1 = acc0, acc2 = acc0, acc3 = acc0;
#pragma unroll 2
  for (int k0 = 0; k0 < 2048; k0 += 32) {
    float4 w0 = *(const float4*)(wrow + k0 + kb);
    float4 w1 = *(const float4*)(wrow + k0 + kb + 4);
    bf16x8 bf;
    bf[0] = (short)f2bf(w0.x); bf[1] = (short)f2bf(w0.y);
    bf[2] = (short)f2bf(w0.z); bf[3] = (short)f2bf(w0.w);
    bf[4] = (short)f2bf(w1.x); bf[5] = (short)f2bf(w1.y);
    bf[6] = (short)f2bf(w1.z); bf[7] = (short)f2bf(w1.w);
    bf16x8 a0 = *(const bf16x8*)(ar0 + k0);
    bf16x8 a1 = *(const bf16x8*)(ar1 + k0);
    bf16x8 a2 = *(const bf16x8*)(ar2 + k0);
    bf16x8 a3 = *(const bf16x8*)(ar3 + k0);
    acc0 = __builtin_amdgcn_mfma_f32_16x16x32_bf16(a0, bf, acc0, 0, 0, 0);
    acc1 = __builtin_amdgcn_mfma_f32_16x16x32_bf16(a1, bf, acc1, 0, 0, 0);
    acc2 = __builtin_amdgcn_mfma_f32_16x16x32_bf16(a2, bf, acc2, 0, 0, 0);
    acc3 = __builtin_amdgcn_mfma_f32_16x16x32_bf16(a3, bf, acc3, 0, 0, 0);
  }
  if (valid) {
    float bias = bo[n];
    int rbase = (lane >> 4) * 4;
#pragma unroll
    for (int r = 0; r < 4; ++r) {
      out[(long)(0 * 16 + rbase + r) * Vdim + n] = tanhf(acc0[r] + bias);
      out[(long)(1 * 16 + rbase + r) * Vdim + n] = tanhf(acc1[r] + bias);
      out[(long)(2 * 16 + rbase + r) * Vdim + n] = tanhf(acc2[r] + bias);
      out[(long)(3 * 16 + rbase + r) * Vdim + n] = tanhf(acc3[r] + bias);
    }
  }
}

// ---------------- log_softmax stage 1: per-chunk online max/sumexp ----------
__global__ void k_lsm_part(const float* __restrict__ out, float* __restrict__ mlp) {
  int b = blockIdx.x, c = blockIdx.y;  // 4 chunks
  int tid = threadIdx.x;
  const int chunk = (Vdim + 3) / 4;
  int v0 = c * chunk, v1 = min(v0 + chunk, Vdim);
  const float* row = out + (long)b * Vdim;
  float m = -INFINITY, l = 0.f;
  for (int v = v0 + tid; v < v1; v += 256) {
    float x = row[v];
    float mn = fmaxf(m, x);
    l = l * __expf(m - mn) + __expf(x - mn);
    m = mn;
  }
#pragma unroll
  for (int off = 1; off < 64; off <<= 1) {
    float mo = __shfl_xor(m, off, 64);
    float lo = __shfl_xor(l, off, 64);
    float M = fmaxf(m, mo);
    l = l * __expf(m - M) + lo * __expf(mo - M);
    m = M;
  }
  __shared__ float sm[4], sl[4];
  if ((tid & 63) == 0) { sm[tid >> 6] = m; sl[tid >> 6] = l; }
  __syncthreads();
  if (tid == 0) {
    float M = fmaxf(fmaxf(sm[0], sm[1]), fmaxf(sm[2], sm[3]));
    float L = sl[0] * __expf(sm[0] - M) + sl[1] * __expf(sm[1] - M)
            + sl[2] * __expf(sm[2] - M) + sl[3] * __expf(sm[3] - M);
    mlp[((long)b * 4 + c) * 2] = M;
    mlp[((long)b * 4 + c) * 2 + 1] = L;
  }
}

// ---------------- log_softmax stage 2: subtract ----------------
__global__ void k_lsm_final(float* __restrict__ out, const float* __restrict__ mlp) {
  int b = blockIdx.x, c = blockIdx.y;  // 8 segments
  float M = -INFINITY;
#pragma unroll
  for (int i = 0; i < 4; ++i) M = fmaxf(M, mlp[((long)b * 4 + i) * 2]);
  float L = 0.f;
#pragma unroll
  for (int i = 0; i < 4; ++i)
    L += mlp[((long)b * 4 + i) * 2 + 1] * __expf(mlp[((long)b * 4 + i) * 2] - M);
  float lg = M + logf(L);
  const int seg = (Vdim + 7) / 8;
  int v0 = c * seg, v1 = min(v0 + seg, Vdim);
  float* row = out + (long)b * Vdim;
  for (int v = v0 + threadIdx.x; v < v1; v += 256) row[v] -= lg;
}

extern "C" void kernel_launch(void* const* d_in, const int* in_sizes, int n_in,
                              void* d_out, int out_size, void* d_ws, size_t ws_size,
                              hipStream_t stream) {
  const int* inputs   = (const int*)d_in[0];
  const float* hidden = (const float*)d_in[1];
  const float* context= (const float*)d_in[2];
  const float* enc    = (const float*)d_in[3];
  const float* E      = (const float*)d_in[4];
  const float* W_ih0  = (const float*)d_in[5];
  const float* W_hh0  = (const float*)d_in[6];
  const float* b_ih0  = (const float*)d_in[7];
  const float* b_hh0  = (const float*)d_in[8];
  const float* W_ih1  = (const float*)d_in[9];
  const float* W_hh1  = (const float*)d_in[10];
  const float* b_ih1  = (const float*)d_in[11];
  const float* b_hh1  = (const float*)d_in[12];
  const float* Wa     = (const float*)d_in[13];
  const float* ba     = (const float*)d_in[14];
  const float* Wo     = (const float*)d_in[15];
  const float* bo     = (const float*)d_in[16];

  float* ws = (float*)d_ws;
  float* x_buf   = ws;                         // 131072
  float* emb     = x_buf + 131072;             // 65536
  float* gi_part = emb + 65536;                // 8*196608 = 1572864
  float* gh_part = gi_part + 1572864;          // 4*196608 = 786432
  float* h0      = gh_part + 786432;           // 65536
  float* h1      = h0 + 65536;                 // 65536
  float* q_part  = h1 + 65536;                 // 8*65536 = 524288
  float* q       = q_part + 524288;            // 65536
  float* scoresp = q + 65536;                  // 131072
  float* cbp     = scoresp + 131072;           // 64
  float* ml      = cbp + 64;                   // 128
  float* lsmml   = ml + 128;                   // 512
  float* part    = lsmml + 512;                // 64*32*1028 = 2105344
  unsigned short* catb = (unsigned short*)(part + 2105344);  // 64*2048 bf16

  float* out0 = (float*)d_out;                       // [B, V]
  float* out1 = out0 + (size_t)Bdim * Vdim;          // [2, B, H]
  float* out2 = out1 + (size_t)2 * Bdim * Hdim;      // [B, H]
  float* out3 = out2 + (size_t)Bdim * Hdim;          // [B, T]

  k_embed_concat<<<256, 256, 0, stream>>>(inputs, E, context, x_buf, emb);

  // GRU layer 0
  k_gemm_sk<false><<<dim3(48, 8), 256, 0, stream>>>(x_buf, 2 * Hdim, W_ih0, 2 * Hdim, gi_part, 3 * Hdim, 3 * Hdim, 256);
  k_gemm_sk<false><<<dim3(48, 4), 256, 0, stream>>>(hidden, Hdim, W_hh0, Hdim, gh_part, 3 * Hdim, 3 * Hdim, 256);
  k_gru_gate2<<<256, 256, 0, stream>>>(gi_part, 8, gh_part, 4, b_ih0, b_hh0, hidden, h0);

  // GRU layer 1
  k_gemm_sk<false><<<dim3(48, 4), 256, 0, stream>>>(h0, Hdim, W_ih1, Hdim, gi_part, 3 * Hdim, 3 * Hdim, 256);
  k_gemm_sk<false><<<dim3(48, 4), 256, 0, stream>>>(hidden + Bdim * Hdim, Hdim, W_hh1, Hdim, gh_part, 3 * Hdim, 3 * Hdim, 256);
  k_gru_gate2<<<256, 256, 0, stream>>>(gi_part, 4, gh_part, 4, b_ih1, b_hh1, hidden + Bdim * Hdim, h1);

  k_hidden_out<<<512, 256, 0, stream>>>(h0, h1, emb, out1);
  k_h1_to_catb<<<64, 256, 0, stream>>>(h1, catb);

  // q = h1 @ Wa, split-K 8x128
  k_gemm_sk<true><<<dim3(16, 8), 256, 0, stream>>>(h1, Hdim, Wa, Hdim, q_part, Hdim, Hdim, 128);
  k_qcomb<<<256, 256, 0, stream>>>(q_part, q);
  k_cb<<<64, 256, 0, stream>>>(h1, ba, cbp);

  dim3 gsc(NCHUNK, Bdim);
  k_scores_ctx<<<gsc, 256, 0, stream>>>(enc, q, cbp, scoresp, part);
  k_ctx_combine<<<64, 256, 0, stream>>>(part, out2, catb, ml);
  k_attn<<<512, 256, 0, stream>>>(scoresp, ml, out3);

  // logits = tanh(catb @ Wo.T + bo) via bf16 MFMA, then two-stage log_softmax
  k_wo_mfma<<<786, 256, 0, stream>>>(catb, Wo, bo, out0);
  k_lsm_part<<<dim3(64, 4), 256, 0, stream>>>(out0, lsmml);
  k_lsm_final<<<dim3(64, 8), 256, 0, stream>>>(out0, lsmml);
}

// Round 4
// 384.035 us; speedup vs baseline: 1.1807x; 1.1807x over previous
//
#include <hip/hip_runtime.h>
#include <hip/hip_bf16.h>
#include <math.h>

#define Hdim 1024
#define Vdim 50257
#define Bdim 64
#define Tdim 2048

#define TCH 64
#define NCHUNK (Tdim / TCH)  // 32
#define PSTRIDE (Hdim + 4)

typedef short bf16x8 __attribute__((ext_vector_type(8)));
typedef float f32x4 __attribute__((ext_vector_type(4)));

__device__ __forceinline__ unsigned short f2bf(float f) {
  unsigned int u = __float_as_uint(f);
  unsigned int r = u + 0x7FFFu + ((u >> 16) & 1u);  // RNE
  return (unsigned short)(r >> 16);
}

// ---------------- fused GRU GEMM (both ih and hh jobs in one launch) --------
// blockIdx.y < nSplitI: gi partial, A = FUSED ? [E[idx]|context] : Ai ; W = Wi
// else:                 gh partial, A = Ah ; W = Wh
// kLen = 256 (16 iterations), register-prefetched single-LDS-buffer loop.
template <bool FUSED>
__global__ __launch_bounds__(256) void k_gru_gemm(
    const int* __restrict__ idx, const float* __restrict__ Ai,
    const float* __restrict__ ctx, const float* __restrict__ Ah,
    const float* __restrict__ Wi, const float* __restrict__ Wh,
    float* __restrict__ gi_part, float* __restrict__ gh_part, int nSplitI) {
  __shared__ float As[16][68];
  __shared__ float Ws[16][68];
  int tid = threadIdx.x;
  bool isI = (int)blockIdx.y < nSplitI;
  int split = isI ? blockIdx.y : (blockIdx.y - nSplitI);
  const float* W = isI ? Wi : Wh;
  int ldw = (FUSED && isI) ? 2048 : 1024;
  int kBase = split * 256;
  int tx = tid & 15, ty = tid >> 4;
  int n0 = blockIdx.x * 64;

  int am = tid >> 2, akk = (tid & 3) << 2;
  int wn = tid >> 2, wkk = (tid & 3) << 2;

  float acc[4][4];
#pragma unroll
  for (int i = 0; i < 4; i++)
#pragma unroll
    for (int j = 0; j < 4; j++) acc[i][j] = 0.f;

  float4 aReg, wReg;
  auto loadTile = [&](int k0) {
    int kg = k0 + akk;
    const float* asrc;
    if (isI) {
      if (FUSED)
        asrc = (kg < 1024) ? (Ai + (long)idx[am] * 1024 + kg)
                           : (ctx + (long)am * 1024 + (kg - 1024));
      else
        asrc = Ai + (long)am * 1024 + kg;
    } else {
      asrc = Ah + (long)am * 1024 + kg;
    }
    aReg = *(const float4*)asrc;
    wReg = *(const float4*)(W + (long)(n0 + wn) * ldw + k0 + wkk);
  };

  loadTile(kBase);
  for (int it = 0; it < 16; ++it) {
    if (it) __syncthreads();  // previous compute finished reading LDS
    As[akk + 0][am] = aReg.x; As[akk + 1][am] = aReg.y;
    As[akk + 2][am] = aReg.z; As[akk + 3][am] = aReg.w;
    Ws[wkk + 0][wn] = wReg.x; Ws[wkk + 1][wn] = wReg.y;
    Ws[wkk + 2][wn] = wReg.z; Ws[wkk + 3][wn] = wReg.w;
    __syncthreads();
    if (it + 1 < 16) loadTile(kBase + (it + 1) * 16);  // in flight during compute
#pragma unroll
    for (int k = 0; k < 16; ++k) {
      float4 a = *(const float4*)&As[k][ty << 2];
      float4 w = *(const float4*)&Ws[k][tx << 2];
      acc[0][0] += a.x * w.x; acc[0][1] += a.x * w.y; acc[0][2] += a.x * w.z; acc[0][3] += a.x * w.w;
      acc[1][0] += a.y * w.x; acc[1][1] += a.y * w.y; acc[1][2] += a.y * w.z; acc[1][3] += a.y * w.w;
      acc[2][0] += a.z * w.x; acc[2][1] += a.z * w.y; acc[2][2] += a.z * w.z; acc[2][3] += a.z * w.w;
      acc[3][0] += a.w * w.x; acc[3][1] += a.w * w.y; acc[3][2] += a.w * w.z; acc[3][3] += a.w * w.w;
    }
  }
  float* C = (isI ? gi_part : gh_part) + (long)split * 64 * 3072;
#pragma unroll
  for (int i = 0; i < 4; i++) {
    int m = (ty << 2) + i;
#pragma unroll
    for (int j = 0; j < 4; j++) {
      int n = n0 + (tx << 2) + j;
      C[(long)m * 3072 + n] = acc[i][j];
    }
  }
}

// ---------------- GRU gate + split-K combine + fused outputs ----------------
// hout = gate(gi,gh,hprev); out1_layer = hout + E[idx]; optional catb = bf16(hout)
__global__ void k_gate(const float* __restrict__ gi_part, int ski,
                       const float* __restrict__ gh_part, int skh,
                       const float* __restrict__ b_ih, const float* __restrict__ b_hh,
                       const float* __restrict__ hprev,
                       const int* __restrict__ idx, const float* __restrict__ E,
                       float* __restrict__ hout, float* __restrict__ out1_layer,
                       unsigned short* __restrict__ catb) {
  int i = blockIdx.x * blockDim.x + threadIdx.x;
  if (i >= Bdim * Hdim) return;
  int b = i >> 10, h = i & 1023;
  float ir = b_ih[h], iz = b_ih[Hdim + h], in = b_ih[2 * Hdim + h];
  float hr = b_hh[h], hz = b_hh[Hdim + h], hn = b_hh[2 * Hdim + h];
  for (int s = 0; s < ski; ++s) {
    const float* g = gi_part + ((long)s * 64 + b) * 3072;
    ir += g[h]; iz += g[Hdim + h]; in += g[2 * Hdim + h];
  }
  for (int s = 0; s < skh; ++s) {
    const float* g = gh_part + ((long)s * 64 + b) * 3072;
    hr += g[h]; hz += g[Hdim + h]; hn += g[2 * Hdim + h];
  }
  float r = 1.f / (1.f + __expf(-(ir + hr)));
  float z = 1.f / (1.f + __expf(-(iz + hz)));
  float n = tanhf(in + r * hn);
  float hv = (1.f - z) * n + z * hprev[i];
  hout[i] = hv;
  out1_layer[i] = hv + E[(long)idx[b] * 1024 + h];
  if (catb) catb[(long)b * 2048 + h] = f2bf(hv);
}

// ---------------- q = h1 @ Wa (TRANSW), split-K 4x256, reg-prefetch ---------
__global__ __launch_bounds__(256) void k_qgemm(const float* __restrict__ A,
                                               const float* __restrict__ W,
                                               float* __restrict__ Cpart) {
  __shared__ float As[16][68];
  __shared__ float Ws[16][68];
  int tid = threadIdx.x;
  int tx = tid & 15, ty = tid >> 4;
  int n0 = blockIdx.x * 64;
  int kBase = blockIdx.y * 256;
  int am = tid >> 2, akk = (tid & 3) << 2;
  int wkk = tid >> 4, wn4 = (tid & 15) << 2;

  float acc[4][4];
#pragma unroll
  for (int i = 0; i < 4; i++)
#pragma unroll
    for (int j = 0; j < 4; j++) acc[i][j] = 0.f;

  float4 aReg, wReg;
  auto loadTile = [&](int k0) {
    aReg = *(const float4*)(A + (long)am * 1024 + k0 + akk);
    wReg = *(const float4*)(W + (long)(k0 + wkk) * 1024 + n0 + wn4);
  };

  loadTile(kBase);
  for (int it = 0; it < 16; ++it) {
    if (it) __syncthreads();
    As[akk + 0][am] = aReg.x; As[akk + 1][am] = aReg.y;
    As[akk + 2][am] = aReg.z; As[akk + 3][am] = aReg.w;
    *(float4*)&Ws[wkk][wn4] = wReg;
    __syncthreads();
    if (it + 1 < 16) loadTile(kBase + (it + 1) * 16);
#pragma unroll
    for (int k = 0; k < 16; ++k) {
      float4 a = *(const float4*)&As[k][ty << 2];
      float4 w = *(const float4*)&Ws[k][tx << 2];
      acc[0][0] += a.x * w.x; acc[0][1] += a.x * w.y; acc[0][2] += a.x * w.z; acc[0][3] += a.x * w.w;
      acc[1][0] += a.y * w.x; acc[1][1] += a.y * w.y; acc[1][2] += a.y * w.z; acc[1][3] += a.y * w.w;
      acc[2][0] += a.z * w.x; acc[2][1] += a.z * w.y; acc[2][2] += a.z * w.z; acc[2][3] += a.z * w.w;
      acc[3][0] += a.w * w.x; acc[3][1] += a.w * w.y; acc[3][2] += a.w * w.z; acc[3][3] += a.w * w.w;
    }
  }
  float* C = Cpart + (long)blockIdx.y * 65536;
#pragma unroll
  for (int i = 0; i < 4; i++) {
    int m = (ty << 2) + i;
#pragma unroll
    for (int j = 0; j < 4; j++) {
      int n = n0 + (tx << 2) + j;
      C[(long)m * 1024 + n] = acc[i][j];
    }
  }
}

// ---------------- q combine + cb[b] = h1[b,:].ba ----------------
__global__ void k_qcb(const float* __restrict__ q_part, const float* __restrict__ h1,
                      const float* __restrict__ ba, float* __restrict__ q,
                      float* __restrict__ cb) {
  int b = blockIdx.x, tid = threadIdx.x;  // 64 blocks x 256
  float4 a = make_float4(0, 0, 0, 0);
#pragma unroll
  for (int s = 0; s < 4; ++s) {
    float4 v = ((const float4*)(q_part + (long)s * 65536 + b * 1024))[tid];
    a.x += v.x; a.y += v.y; a.z += v.z; a.w += v.w;
  }
  ((float4*)(q + (long)b * 1024))[tid] = a;
  float4 hv = ((const float4*)(h1 + (long)b * 1024))[tid];
  float4 bv = ((const float4*)ba)[tid];
  float p = hv.x * bv.x + hv.y * bv.y + hv.z * bv.z + hv.w * bv.w;
#pragma unroll
  for (int off = 32; off > 0; off >>= 1) p += __shfl_down(p, off, 64);
  __shared__ float red[4];
  if ((tid & 63) == 0) red[tid >> 6] = p;
  __syncthreads();
  if (tid == 0) cb[b] = red[0] + red[1] + red[2] + red[3];
}

// ---------------- scores + online-softmax partial context (wave-per-row) ----
__global__ __launch_bounds__(256) void k_scores_ctx(
    const float* __restrict__ enc, const float* __restrict__ q,
    const float* __restrict__ cb, float* __restrict__ scores,
    float* __restrict__ part) {
  int b = blockIdx.y, ch = blockIdx.x;
  int tid = threadIdx.x, w = tid >> 6, lane = tid & 63;
  __shared__ float s_acc[4][Hdim];
  __shared__ float s_ml[4][2];
  const float4* q4 = (const float4*)(q + (long)b * Hdim);
  float4 q0 = q4[lane], q1 = q4[lane + 64], q2 = q4[lane + 128], q3 = q4[lane + 192];
  float cbb = cb[b];
  float m = -INFINITY, l = 0.f;
  float4 a0 = make_float4(0, 0, 0, 0), a1 = a0, a2 = a0, a3 = a0;
  int tbase = ch * TCH + w * 16;
  for (int i = 0; i < 16; ++i) {
    int t = tbase + i;
    const float4* e4 = (const float4*)(enc + ((long)t * Bdim + b) * Hdim);
    float4 e0 = e4[lane], e1 = e4[lane + 64], e2 = e4[lane + 128], e3 = e4[lane + 192];
    float p = q0.x * e0.x + q0.y * e0.y + q0.z * e0.z + q0.w * e0.w
            + q1.x * e1.x + q1.y * e1.y + q1.z * e1.z + q1.w * e1.w
            + q2.x * e2.x + q2.y * e2.y + q2.z * e2.z + q2.w * e2.w
            + q3.x * e3.x + q3.y * e3.y + q3.z * e3.z + q3.w * e3.w;
#pragma unroll
    for (int off = 1; off < 64; off <<= 1) p += __shfl_xor(p, off, 64);
    float s = p + cbb;
    if (lane == 0) scores[(long)b * Tdim + t] = s;
    float mn = fmaxf(m, s);
    float sc = __expf(m - mn);
    float wt = __expf(s - mn);
    l = l * sc + wt;
    a0.x = a0.x * sc + wt * e0.x; a0.y = a0.y * sc + wt * e0.y;
    a0.z = a0.z * sc + wt * e0.z; a0.w = a0.w * sc + wt * e0.w;
    a1.x = a1.x * sc + wt * e1.x; a1.y = a1.y * sc + wt * e1.y;
    a1.z = a1.z * sc + wt * e1.z; a1.w = a1.w * sc + wt * e1.w;
    a2.x = a2.x * sc + wt * e2.x; a2.y = a2.y * sc + wt * e2.y;
    a2.z = a2.z * sc + wt * e2.z; a2.w = a2.w * sc + wt * e2.w;
    a3.x = a3.x * sc + wt * e3.x; a3.y = a3.y * sc + wt * e3.y;
    a3.z = a3.z * sc + wt * e3.z; a3.w = a3.w * sc + wt * e3.w;
    m = mn;
  }
  float4* sa = (float4*)s_acc[w];
  sa[lane] = a0; sa[lane + 64] = a1; sa[lane + 128] = a2; sa[lane + 192] = a3;
  if (lane == 0) { s_ml[w][0] = m; s_ml[w][1] = l; }
  __syncthreads();
  float M = fmaxf(fmaxf(s_ml[0][0], s_ml[1][0]), fmaxf(s_ml[2][0], s_ml[3][0]));
  float L = 0.f;
  float4 o = make_float4(0, 0, 0, 0);
  for (int ww = 0; ww < 4; ++ww) {
    float wgt = __expf(s_ml[ww][0] - M);
    L += wgt * s_ml[ww][1];
    float4 v = ((const float4*)s_acc[ww])[tid];
    o.x += wgt * v.x; o.y += wgt * v.y; o.z += wgt * v.z; o.w += wgt * v.w;
  }
  float* pp = part + ((long)b * NCHUNK + ch) * PSTRIDE;
  ((float4*)pp)[tid] = o;
  if (tid == 0) { pp[Hdim] = M; pp[Hdim + 1] = L; }
}

// ---------------- combine partials -> context + catb + attn output ----------
__global__ void k_ctx_combine(const float* __restrict__ part,
                              const float* __restrict__ scores,
                              float* __restrict__ ctx_out,
                              unsigned short* __restrict__ catb,
                              float* __restrict__ attn_out) {
  int b = blockIdx.x, tid = threadIdx.x;  // 256
  __shared__ float ms[NCHUNK], ls[NCHUNK];
  if (tid < NCHUNK) {
    const float* pp = part + ((long)b * NCHUNK + tid) * PSTRIDE;
    ms[tid] = pp[Hdim];
    ls[tid] = pp[Hdim + 1];
  }
  __syncthreads();
  float m = -INFINITY;
  for (int c = 0; c < NCHUNK; ++c) m = fmaxf(m, ms[c]);
  float l = 0.f;
  for (int c = 0; c < NCHUNK; ++c) l += __expf(ms[c] - m) * ls[c];
  float4 a = make_float4(0, 0, 0, 0);
  for (int c = 0; c < NCHUNK; ++c) {
    float w = __expf(ms[c] - m);
    float4 v = ((const float4*)(part + ((long)b * NCHUNK + c) * PSTRIDE))[tid];
    a.x += w * v.x; a.y += w * v.y; a.z += w * v.z; a.w += w * v.w;
  }
  float inv = 1.f / l;
  a.x *= inv; a.y *= inv; a.z *= inv; a.w *= inv;
  ((float4*)(ctx_out + (long)b * Hdim))[tid] = a;
  ushort4 o;
  o.x = f2bf(a.x); o.y = f2bf(a.y); o.z = f2bf(a.z); o.w = f2bf(a.w);
  *(ushort4*)(catb + (long)b * 2 * Hdim + Hdim + tid * 4) = o;
  // attention weights output for this row
  const float* srow = scores + (long)b * Tdim;
  float* arow = attn_out + (long)b * Tdim;
  for (int t = tid; t < Tdim; t += 256) arow[t] = __expf(srow[t] - m) * inv;
}

// ---------------- Wo GEMM: bf16 MFMA, 32-col 2-wave blocks ----------------
__global__ __launch_bounds__(128) void k_wo_mfma(const unsigned short* __restrict__ catb,
                                                 const float* __restrict__ Wo,
                                                 const float* __restrict__ bo,
                                                 float* __restrict__ out) {
  int tid = threadIdx.x, w = tid >> 6, lane = tid & 63;
  int n = blockIdx.x * 32 + w * 16 + (lane & 15);
  bool valid = n < Vdim;
  const float* wrow = Wo + (long)(valid ? n : 0) * (2 * Hdim);
  int kb = (lane >> 4) * 8;
  int r16 = lane & 15;
  const unsigned short* ar0 = catb + (long)(r16) * 2048 + kb;
  const unsigned short* ar1 = catb + (long)(16 + r16) * 2048 + kb;
  const unsigned short* ar2 = catb + (long)(32 + r16) * 2048 + kb;
  const unsigned short* ar3 = catb + (long)(48 + r16) * 2048 + kb;
  f32x4 acc0 = {0.f, 0.f, 0.f, 0.f}, acc1 = acc0, acc2 = acc0, acc3 = acc0;
#pragma unroll 2
  for (int k0 = 0; k0 < 2048; k0 += 32) {
    float4 w0 = *(const float4*)(wrow + k0 + kb);
    float4 w1 = *(const float4*)(wrow + k0 + kb + 4);
    bf16x8 bf;
    bf[0] = (short)f2bf(w0.x); bf[1] = (short)f2bf(w0.y);
    bf[2] = (short)f2bf(w0.z); bf[3] = (short)f2bf(w0.w);
    bf[4] = (short)f2bf(w1.x); bf[5] = (short)f2bf(w1.y);
    bf[6] = (short)f2bf(w1.z); bf[7] = (short)f2bf(w1.w);
    bf16x8 a0 = *(const bf16x8*)(ar0 + k0);
    bf16x8 a1 = *(const bf16x8*)(ar1 + k0);
    bf16x8 a2 = *(const bf16x8*)(ar2 + k0);
    bf16x8 a3 = *(const bf16x8*)(ar3 + k0);
    acc0 = __builtin_amdgcn_mfma_f32_16x16x32_bf16(a0, bf, acc0, 0, 0, 0);
    acc1 = __builtin_amdgcn_mfma_f32_16x16x32_bf16(a1, bf, acc1, 0, 0, 0);
    acc2 = __builtin_amdgcn_mfma_f32_16x16x32_bf16(a2, bf, acc2, 0, 0, 0);
    acc3 = __builtin_amdgcn_mfma_f32_16x16x32_bf16(a3, bf, acc3, 0, 0, 0);
  }
  if (valid) {
    float bias = bo[n];
    int rbase = (lane >> 4) * 4;
#pragma unroll
    for (int r = 0; r < 4; ++r) {
      out[(long)(0 * 16 + rbase + r) * Vdim + n] = tanhf(acc0[r] + bias);
      out[(long)(1 * 16 + rbase + r) * Vdim + n] = tanhf(acc1[r] + bias);
      out[(long)(2 * 16 + rbase + r) * Vdim + n] = tanhf(acc2[r] + bias);
      out[(long)(3 * 16 + rbase + r) * Vdim + n] = tanhf(acc3[r] + bias);
    }
  }
}

// ---------------- log_softmax stage 1: per-chunk max/sumexp ----------
__global__ void k_lsm_part(const float* __restrict__ out, float* __restrict__ mlp) {
  int b = blockIdx.x, c = blockIdx.y;  // 4 chunks
  int tid = threadIdx.x;
  const int chunk = (Vdim + 3) / 4;
  int v0 = c * chunk, v1 = min(v0 + chunk, Vdim);
  const float* row = out + (long)b * Vdim;
  float m = -INFINITY, l = 0.f;
  for (int v = v0 + tid; v < v1; v += 256) {
    float x = row[v];
    float mn = fmaxf(m, x);
    l = l * __expf(m - mn) + __expf(x - mn);
    m = mn;
  }
#pragma unroll
  for (int off = 1; off < 64; off <<= 1) {
    float mo = __shfl_xor(m, off, 64);
    float lo = __shfl_xor(l, off, 64);
    float M = fmaxf(m, mo);
    l = l * __expf(m - M) + lo * __expf(mo - M);
    m = M;
  }
  __shared__ float sm[4], sl[4];
  if ((tid & 63) == 0) { sm[tid >> 6] = m; sl[tid >> 6] = l; }
  __syncthreads();
  if (tid == 0) {
    float M = fmaxf(fmaxf(sm[0], sm[1]), fmaxf(sm[2], sm[3]));
    float L = sl[0] * __expf(sm[0] - M) + sl[1] * __expf(sm[1] - M)
            + sl[2] * __expf(sm[2] - M) + sl[3] * __expf(sm[3] - M);
    mlp[((long)b * 4 + c) * 2] = M;
    mlp[((long)b * 4 + c) * 2 + 1] = L;
  }
}

// ---------------- log_softmax stage 2: subtract ----------------
__global__ void k_lsm_final(float* __restrict__ out, const float* __restrict__ mlp) {
  int b = blockIdx.x, c = blockIdx.y;  // 8 segments
  float M = -INFINITY;
#pragma unroll
  for (int i = 0; i < 4; ++i) M = fmaxf(M, mlp[((long)b * 4 + i) * 2]);
  float L = 0.f;
#pragma unroll
  for (int i = 0; i < 4; ++i)
    L += mlp[((long)b * 4 + i) * 2 + 1] * __expf(mlp[((long)b * 4 + i) * 2] - M);
  float lg = M + logf(L);
  const int seg = (Vdim + 7) / 8;
  int v0 = c * seg, v1 = min(v0 + seg, Vdim);
  float* row = out + (long)b * Vdim;
  for (int v = v0 + threadIdx.x; v < v1; v += 256) row[v] -= lg;
}

extern "C" void kernel_launch(void* const* d_in, const int* in_sizes, int n_in,
                              void* d_out, int out_size, void* d_ws, size_t ws_size,
                              hipStream_t stream) {
  const int* inputs   = (const int*)d_in[0];
  const float* hidden = (const float*)d_in[1];
  const float* context= (const float*)d_in[2];
  const float* enc    = (const float*)d_in[3];
  const float* E      = (const float*)d_in[4];
  const float* W_ih0  = (const float*)d_in[5];
  const float* W_hh0  = (const float*)d_in[6];
  const float* b_ih0  = (const float*)d_in[7];
  const float* b_hh0  = (const float*)d_in[8];
  const float* W_ih1  = (const float*)d_in[9];
  const float* W_hh1  = (const float*)d_in[10];
  const float* b_ih1  = (const float*)d_in[11];
  const float* b_hh1  = (const float*)d_in[12];
  const float* Wa     = (const float*)d_in[13];
  const float* ba     = (const float*)d_in[14];
  const float* Wo     = (const float*)d_in[15];
  const float* bo     = (const float*)d_in[16];

  float* ws = (float*)d_ws;
  float* gi_part = ws;                         // 8*64*3072 = 1572864
  float* gh_part = gi_part + 1572864;          // 4*64*3072 = 786432
  float* h0      = gh_part + 786432;           // 65536
  float* h1      = h0 + 65536;                 // 65536
  float* q_part  = h1 + 65536;                 // 4*65536 = 262144
  float* q       = q_part + 262144;            // 65536
  float* scoresp = q + 65536;                  // 131072
  float* cbp     = scoresp + 131072;           // 64
  float* lsmml   = cbp + 64;                   // 512
  float* part    = lsmml + 512;                // 64*32*1028 = 2105344
  unsigned short* catb = (unsigned short*)(part + 2105344);  // 64*2048 bf16

  float* out0 = (float*)d_out;                       // [B, V]
  float* out1 = out0 + (size_t)Bdim * Vdim;          // [2, B, H]
  float* out2 = out1 + (size_t)2 * Bdim * Hdim;      // [B, H]
  float* out3 = out2 + (size_t)Bdim * Hdim;          // [B, T]

  // GRU layer 0: gi (8 splits, fused [E|context] A) + gh (4 splits) in one launch
  k_gru_gemm<true><<<dim3(48, 12), 256, 0, stream>>>(
      inputs, E, context, hidden, W_ih0, W_hh0, gi_part, gh_part, 8);
  k_gate<<<256, 256, 0, stream>>>(gi_part, 8, gh_part, 4, b_ih0, b_hh0, hidden,
                                  inputs, E, h0, out1, nullptr);

  // GRU layer 1: gi (4 splits, A=h0) + gh (4 splits, A=hidden[1])
  k_gru_gemm<false><<<dim3(48, 8), 256, 0, stream>>>(
      inputs, h0, nullptr, hidden + Bdim * Hdim, W_ih1, W_hh1, gi_part, gh_part, 4);
  k_gate<<<256, 256, 0, stream>>>(gi_part, 4, gh_part, 4, b_ih1, b_hh1,
                                  hidden + Bdim * Hdim, inputs, E, h1,
                                  out1 + Bdim * Hdim, catb);

  // q = h1 @ Wa (split-K 4x256), then combine + cb
  k_qgemm<<<dim3(16, 4), 256, 0, stream>>>(h1, Wa, q_part);
  k_qcb<<<64, 256, 0, stream>>>(q_part, h1, ba, q, cbp);

  // attention pass over enc
  k_scores_ctx<<<dim3(NCHUNK, Bdim), 256, 0, stream>>>(enc, q, cbp, scoresp, part);
  k_ctx_combine<<<64, 256, 0, stream>>>(part, scoresp, out2, catb, out3);

  // logits = tanh(catb @ Wo.T + bo), then two-stage log_softmax
  k_wo_mfma<<<(Vdim + 31) / 32, 128, 0, stream>>>(catb, Wo, bo, out0);
  k_lsm_part<<<dim3(64, 4), 256, 0, stream>>>(out0, lsmml);
  k_lsm_final<<<dim3(64, 8), 256, 0, stream>>>(out0, lsmml);
}